// Round 3
// baseline (1136.395 us; speedup 1.0000x reference)
//
#include <hip/hip_runtime.h>
#include <math.h>

// Problem constants (fixed by setup_inputs)
constexpr int Bb = 128;   // batch
constexpr int Nn = 2048;  // input capsules
constexpr int Dd = 8;     // input capsule dim
constexpr int Jj = 32;    // output capsules
constexpr int Pp = 16;    // output capsule dim

// Tiling
constexpr int BT = 4;           // batches per wave register tile
constexpr int WV = 4;           // waves per block
constexpr int BB = BT * WV;     // 16 batches per block
constexpr int BN = 16;          // n per block
constexpr int NBC = Bb / BB;    // 8 batch-chunks
constexpr int NNC = Nn / BN;    // 128 n-chunks
constexpr int GRID = NBC * NNC; // 1024 blocks
constexpr int SZ = Bb * Jj * Pp;            // 65536 floats
constexpr int WSLICE_F4 = Jj * Pp * Dd / 4; // 1024 float4 per n-slice (16 KB)

typedef float v2f __attribute__((ext_vector_type(2)));

// Routing pass kernel. W staged per-n in LDS (swizzled, conflict-free),
// double-buffered, with depth-2 register prefetch. XCD-aware block swizzle:
// the 8 batch-chunk blocks sharing an n-chunk land on the same XCD so W is
// HBM-fetched once and L2-served to the other 7.
template<int LOGITS, int ATOMIC>
__global__ __launch_bounds__(256, 4)
void route_k(const float* __restrict__ x, const float* __restrict__ W,
             const float* __restrict__ OS, float* __restrict__ S)
{
    __shared__ float4 wbuf[2][WSLICE_F4];   // 2 x 16 KB W double buffer
    __shared__ float  xs[BB * BN * Dd];     // 8 KB x tile [b][n][d]

    const int tid  = threadIdx.x;
    const int wave = tid >> 6;
    const int lane = tid & 63;

    // XCD swizzle: xcd = blockIdx%8 (round-robin dispatch). Blocks with the
    // same nc share blockIdx%8 -> same XCD L2.
    const int q   = blockIdx.x;
    const int xcd = q & 7;
    const int r   = q >> 3;
    const int bc  = r & 7;          // batch-chunk 0..7
    const int ncg = r >> 3;         // 0..15
    const int nc  = xcd + 8 * ncg;  // n-chunk 0..127
    const int b0  = bc * BB;
    const int n0  = nc * BN;
    const int j   = lane >> 1;
    const int hp  = lane & 1;       // p-half

    // ---- stage x tile (coalesced float4) ----
    {
        const int b = tid >> 4, f = tid & 15;
        const float4* src = reinterpret_cast<const float4*>(
            x + ((size_t)(b0 + b) * Nn + n0) * Dd);
        float4* dst = reinterpret_cast<float4*>(xs + (size_t)b * BN * Dd);
        dst[f] = src[f];
        dst[f + 16] = src[f + 16];
    }

    // ---- W staging helpers ----
    const float4* Wg = reinterpret_cast<const float4*>(W);
    const int tg = tid & 31;    // within-j float4 column
    const int th = tid >> 5;    // j base
    const int kk = tid & 15;    // swizzle k
    const int lb = tid >> 4;    // swizzle l base

    float4 st[2][4];            // two register slice buffers (depth-2 prefetch)
    auto load_slice = [&](int n, int sb) {
        const size_t base = (size_t)n * 32 + tg;
        #pragma unroll
        for (int c = 0; c < 4; ++c)
            st[sb][c] = Wg[base + (size_t)(th + 8 * c) * ((size_t)Nn * 32)];
    };
    auto store_slice = [&](int buf, int sb) {
        #pragma unroll
        for (int c = 0; c < 4; ++c)
            wbuf[buf][kk * 64 + ((lb + 16 * c + kk) & 63)] = st[sb][c];
    };

    // Output-sum fragment for logits
    float osum[BT][8];
    if (LOGITS) {
        #pragma unroll
        for (int bb = 0; bb < BT; ++bb) {
            const float4* op = reinterpret_cast<const float4*>(
                OS + ((size_t)(b0 + wave * BT + bb) * Jj + j) * Pp + hp * 8);
            float4 a = op[0], b4 = op[1];
            osum[bb][0] = a.x;  osum[bb][1] = a.y;  osum[bb][2] = a.z;  osum[bb][3] = a.w;
            osum[bb][4] = b4.x; osum[bb][5] = b4.y; osum[bb][6] = b4.z; osum[bb][7] = b4.w;
        }
    }

    float Sa[BT][8];
    #pragma unroll
    for (int bb = 0; bb < BT; ++bb)
        #pragma unroll
        for (int pp = 0; pp < 8; ++pp) Sa[bb][pp] = 0.f;

    // Prologue: slices n0, n0+1 in regs; slice n0 in LDS buf 0
    load_slice(n0, 0);
    load_slice(n0 + 1, 1);
    store_slice(0, 0);
    __syncthreads();

    #pragma unroll 2
    for (int nn = 0; nn < BN; ++nn) {
        if (nn + 2 < BN) load_slice(n0 + nn + 2, nn & 1);  // depth-2 prefetch
        const int buf = nn & 1;

        // x values (LDS broadcast) as float2 pairs for v_pk_fma_f32
        v2f xv[BT][4];
        #pragma unroll
        for (int bb = 0; bb < BT; ++bb) {
            const v2f* xp = reinterpret_cast<const v2f*>(
                xs + ((size_t)(wave * BT + bb) * BN + nn) * Dd);
            #pragma unroll
            for (int d = 0; d < 4; ++d) xv[bb][d] = xp[d];
        }

        // u_hat from swizzled LDS W fragments
        float uh[BT][8];
        #pragma unroll
        for (int pp = 0; pp < 8; ++pp) {
            const int k0 = 2 * pp, k1 = 2 * pp + 1;
            float4 a = wbuf[buf][k0 * 64 + ((lane + k0) & 63)];
            float4 b = wbuf[buf][k1 * 64 + ((lane + k1) & 63)];
            v2f wv0 = {a.x, a.y}, wv1 = {a.z, a.w};
            v2f wv2 = {b.x, b.y}, wv3 = {b.z, b.w};
            #pragma unroll
            for (int bb = 0; bb < BT; ++bb) {
                v2f acc = wv0 * xv[bb][0];
                acc = __builtin_elementwise_fma(wv1, xv[bb][1], acc);
                acc = __builtin_elementwise_fma(wv2, xv[bb][2], acc);
                acc = __builtin_elementwise_fma(wv3, xv[bb][3], acc);
                uh[bb][pp] = acc.x + acc.y;
            }
        }

        if (!LOGITS) {
            #pragma unroll
            for (int bb = 0; bb < BT; ++bb)
                #pragma unroll
                for (int pp = 0; pp < 8; ++pp) Sa[bb][pp] += uh[bb][pp];
        } else {
            #pragma unroll
            for (int bb = 0; bb < BT; ++bb) {
                float lg = 0.f;
                #pragma unroll
                for (int pp = 0; pp < 8; ++pp)
                    lg = fmaf(osum[bb][pp], uh[bb][pp], lg);
                lg += __shfl_xor(lg, 1, 64);   // merge p-halves: full 16-p dot
                // softmax over j, no max-subtraction (|lg| small): butterfly sum
                float e = __expf(lg);
                float se = e;
                #pragma unroll
                for (int mk = 2; mk <= 32; mk <<= 1)
                    se += __shfl_xor(se, mk, 64);
                float c = e * __builtin_amdgcn_rcpf(se);
                #pragma unroll
                for (int pp = 0; pp < 8; ++pp)
                    Sa[bb][pp] = fmaf(c, uh[bb][pp], Sa[bb][pp]);
            }
        }

        if (nn + 1 < BN) {
            store_slice((nn + 1) & 1, (nn + 1) & 1);
            __syncthreads();
        }
    }

    // ---- flush block-partial S ----
    #pragma unroll
    for (int bb = 0; bb < BT; ++bb) {
        const size_t off = ((size_t)(b0 + wave * BT + bb) * Jj + j) * Pp + hp * 8;
        if (ATOMIC) {
            float* sp = S + off;
            #pragma unroll
            for (int pp = 0; pp < 8; ++pp) atomicAdd(sp + pp, Sa[bb][pp]);
        } else {
            float4* dst = reinterpret_cast<float4*>(S + (size_t)nc * SZ + off);
            dst[0] = make_float4(Sa[bb][0], Sa[bb][1], Sa[bb][2], Sa[bb][3]);
            dst[1] = make_float4(Sa[bb][4], Sa[bb][5], Sa[bb][6], Sa[bb][7]);
        }
    }
}

// Reduce nparts partial S slices, then squash.
// mode 0: OS = v; 1: OS += v; 2: out = v.  One thread per float4 (16384).
__global__ void reduce_squash_k(const float* __restrict__ Sp, int nparts,
                                float scale, float* __restrict__ OS,
                                float* __restrict__ out, int mode)
{
    const int t = blockIdx.x * 256 + threadIdx.x;   // 0..16383
    const float4* sp = reinterpret_cast<const float4*>(Sp);
    float4 a = make_float4(0.f, 0.f, 0.f, 0.f);
    #pragma unroll 4
    for (int s = 0; s < nparts; ++s) {
        float4 v = sp[(size_t)s * (SZ / 4) + t];
        a.x += v.x; a.y += v.y; a.z += v.z; a.w += v.w;
    }
    a.x *= scale; a.y *= scale; a.z *= scale; a.w *= scale;
    float s2 = a.x * a.x + a.y * a.y + a.z * a.z + a.w * a.w;
    s2 += __shfl_xor(s2, 1, 64);   // 16 p = 4 consecutive threads
    s2 += __shfl_xor(s2, 2, 64);
    const float g = s2 / ((1.f + s2) * sqrtf(s2 + 1e-7f));
    float4 v = make_float4(g * a.x, g * a.y, g * a.z, g * a.w);
    if (mode == 0) {
        reinterpret_cast<float4*>(OS)[t] = v;
    } else if (mode == 1) {
        float4 o = reinterpret_cast<float4*>(OS)[t];
        o.x += v.x; o.y += v.y; o.z += v.z; o.w += v.w;
        reinterpret_cast<float4*>(OS)[t] = o;
    } else {
        reinterpret_cast<float4*>(out)[t] = v;
    }
}

extern "C" void kernel_launch(void* const* d_in, const int* in_sizes, int n_in,
                              void* d_out, int out_size, void* d_ws, size_t ws_size,
                              hipStream_t stream)
{
    const float* x = (const float*)d_in[0];   // [128, 2048, 8]
    const float* W = (const float*)d_in[1];   // [32, 2048, 16, 8]
    float* out = (float*)d_out;               // [128, 32, 16]

    const bool part = ws_size >= (size_t)(NNC + 1) * SZ * sizeof(float); // ~34 MB
    dim3 rg(GRID), rb(256);
    dim3 sg(SZ / 4 / 256), sb(256);           // 64 blocks x 256

    if (part) {
        float* Sp = (float*)d_ws;                 // [128][65536] partials
        float* OS = Sp + (size_t)NNC * SZ;        // running output sum

        route_k<0, 0><<<rg, rb, 0, stream>>>(x, W, nullptr, Sp);
        reduce_squash_k<<<sg, sb, 0, stream>>>(Sp, NNC, 1.f / Jj, OS, out, 0);

        route_k<1, 0><<<rg, rb, 0, stream>>>(x, W, OS, Sp);
        reduce_squash_k<<<sg, sb, 0, stream>>>(Sp, NNC, 1.f, OS, out, 1);

        route_k<1, 0><<<rg, rb, 0, stream>>>(x, W, OS, Sp);
        reduce_squash_k<<<sg, sb, 0, stream>>>(Sp, NNC, 1.f, OS, out, 2);
    } else {
        float* S  = (float*)d_ws;
        float* OS = S + SZ;
        const size_t Sbytes = (size_t)SZ * sizeof(float);

        hipMemsetAsync(S, 0, Sbytes, stream);
        route_k<0, 1><<<rg, rb, 0, stream>>>(x, W, nullptr, S);
        reduce_squash_k<<<sg, sb, 0, stream>>>(S, 1, 1.f / Jj, OS, out, 0);

        hipMemsetAsync(S, 0, Sbytes, stream);
        route_k<1, 1><<<rg, rb, 0, stream>>>(x, W, OS, S);
        reduce_squash_k<<<sg, sb, 0, stream>>>(S, 1, 1.f, OS, out, 1);

        hipMemsetAsync(S, 0, Sbytes, stream);
        route_k<1, 1><<<rg, rb, 0, stream>>>(x, W, OS, S);
        reduce_squash_k<<<sg, sb, 0, stream>>>(S, 1, 1.f, OS, out, 2);
    }
}

// Round 4
// 341.613 us; speedup vs baseline: 3.3266x; 3.3266x over previous
//
#include <hip/hip_runtime.h>
#include <math.h>

// Problem constants (fixed by setup_inputs)
constexpr int Bb = 128;   // batch
constexpr int Nn = 2048;  // input capsules
constexpr int Dd = 8;     // input capsule dim
constexpr int Jj = 32;    // output capsules
constexpr int Pp = 16;    // output capsule dim

// Tiling: 512-thread blocks, 8 waves, each wave BT=2 batches, all waves share
// the same n-slice. blocks = NBC x NNC = 8 x 64 = 512 (2/CU, 16 waves/CU).
constexpr int BT = 2;            // batches per wave
constexpr int WV = 8;            // waves per block
constexpr int BB = BT * WV;      // 16 batches per block
constexpr int BN = 32;           // n per block
constexpr int NBC = Bb / BB;     // 8 batch-chunks
constexpr int NNC = Nn / BN;     // 64 n-chunks
constexpr int GRID = NBC * NNC;  // 512 blocks
constexpr int SZ = Bb * Jj * Pp;            // 65536 floats
constexpr int WSLICE_F4 = Jj * Pp * Dd / 4; // 1024 float4 per n-slice (16 KB)

typedef float v2f __attribute__((ext_vector_type(2)));

// Routing pass. W staged per-n in LDS (swizzled, conflict-free), double
// buffered. XCD swizzle: the 8 bc-sharers of each n-chunk share blockIdx&7
// (assumed XCD round-robin) so W slices are fetched into one XCD's L2 once.
// Atomic-op budget lesson (R3): atomic count = 65536*NNC; keep NNC work per
// block serial, never raise block count.
template<int LOGITS, int ATOMIC>
__global__ __launch_bounds__(512, 4)
void route_k(const float* __restrict__ x, const float* __restrict__ W,
             const float* __restrict__ OS, float* __restrict__ S)
{
    __shared__ float4 wbuf[2][WSLICE_F4];   // 2 x 16 KB W double buffer
    __shared__ float  xs[BB * BN * Dd];     // 16 KB x tile [b][n][d]

    const int tid  = threadIdx.x;
    const int wave = tid >> 6;
    const int lane = tid & 63;

    // Swizzle: xcd = id&7; bc = (id>>3)&7; nch = id>>6; nc = xcd + 8*nch.
    const int id  = blockIdx.x;
    const int xcd = id & 7;
    const int bc  = (id >> 3) & 7;
    const int nch = id >> 6;               // 0..7
    const int nc  = xcd + 8 * nch;         // 0..63
    const int b0  = bc * BB;
    const int n0  = nc * BN;
    const int j   = lane >> 1;
    const int hp  = lane & 1;              // p-half

    // ---- stage x tile: 16 b x 32 n x 8 d = 1024 float4, 2 per thread ----
    {
        const int b = tid >> 5, f = tid & 31;
        const float4* src = reinterpret_cast<const float4*>(
            x + ((size_t)(b0 + b) * Nn + n0) * Dd);
        float4* dst = reinterpret_cast<float4*>(xs + (size_t)b * BN * Dd);
        dst[f] = src[f];
        dst[f + 32] = src[f + 32];
    }

    // ---- W staging: slice = 1024 float4; thread t handles G = t, t+512 ----
    const float4* Wg = reinterpret_cast<const float4*>(W);
    const int col = tid & 31;    // within-j float4 column (p*2+dh)
    const int jlo = tid >> 5;    // j for G0 (0..15); G1 -> jlo+16
    const int kk  = tid & 15;    // swizzle k (same for G0,G1)
    const int l0  = tid >> 4;    // swizzle l for G0 (0..31); G1 -> l0+32

    float4 st[2];
    auto load_slice = [&](int n) {
        const size_t base = (size_t)n * 32 + col;
        st[0] = Wg[base + (size_t)jlo * ((size_t)Nn * 32)];
        st[1] = Wg[base + (size_t)(jlo + 16) * ((size_t)Nn * 32)];
    };
    auto store_slice = [&](int buf) {
        wbuf[buf][kk * 64 + ((l0 + kk) & 63)]      = st[0];
        wbuf[buf][kk * 64 + ((l0 + 32 + kk) & 63)] = st[1];
    };

    // Output-sum fragment for logits
    float osum[BT][8];
    if (LOGITS) {
        #pragma unroll
        for (int bb = 0; bb < BT; ++bb) {
            const float4* op = reinterpret_cast<const float4*>(
                OS + ((size_t)(b0 + wave * BT + bb) * Jj + j) * Pp + hp * 8);
            float4 a = op[0], b4 = op[1];
            osum[bb][0] = a.x;  osum[bb][1] = a.y;  osum[bb][2] = a.z;  osum[bb][3] = a.w;
            osum[bb][4] = b4.x; osum[bb][5] = b4.y; osum[bb][6] = b4.z; osum[bb][7] = b4.w;
        }
    }

    float Sa[BT][8];
    #pragma unroll
    for (int bb = 0; bb < BT; ++bb)
        #pragma unroll
        for (int pp = 0; pp < 8; ++pp) Sa[bb][pp] = 0.f;

    load_slice(n0);
    store_slice(0);
    __syncthreads();

    for (int nn = 0; nn < BN; ++nn) {
        if (nn + 1 < BN) load_slice(n0 + nn + 1);  // prefetch next slice to regs
        const int buf = nn & 1;

        // x values (LDS broadcast) as float2 pairs for v_pk_fma_f32
        v2f xv[BT][4];
        #pragma unroll
        for (int bb = 0; bb < BT; ++bb) {
            const v2f* xp = reinterpret_cast<const v2f*>(
                xs + ((size_t)(wave * BT + bb) * BN + nn) * Dd);
            #pragma unroll
            for (int d = 0; d < 4; ++d) xv[bb][d] = xp[d];
        }

        // u_hat from swizzled LDS W fragments
        float uh[BT][8];
        #pragma unroll
        for (int pp = 0; pp < 8; ++pp) {
            const int k0 = 2 * pp, k1 = 2 * pp + 1;
            float4 a = wbuf[buf][k0 * 64 + ((lane + k0) & 63)];
            float4 b = wbuf[buf][k1 * 64 + ((lane + k1) & 63)];
            v2f wv0 = {a.x, a.y}, wv1 = {a.z, a.w};
            v2f wv2 = {b.x, b.y}, wv3 = {b.z, b.w};
            #pragma unroll
            for (int bb = 0; bb < BT; ++bb) {
                v2f acc = wv0 * xv[bb][0];
                acc = __builtin_elementwise_fma(wv1, xv[bb][1], acc);
                acc = __builtin_elementwise_fma(wv2, xv[bb][2], acc);
                acc = __builtin_elementwise_fma(wv3, xv[bb][3], acc);
                uh[bb][pp] = acc.x + acc.y;
            }
        }

        if (!LOGITS) {
            #pragma unroll
            for (int bb = 0; bb < BT; ++bb)
                #pragma unroll
                for (int pp = 0; pp < 8; ++pp) Sa[bb][pp] += uh[bb][pp];
        } else {
            #pragma unroll
            for (int bb = 0; bb < BT; ++bb) {
                float lg = 0.f;
                #pragma unroll
                for (int pp = 0; pp < 8; ++pp)
                    lg = fmaf(osum[bb][pp], uh[bb][pp], lg);
                lg += __shfl_xor(lg, 1, 64);   // merge p-halves: full 16-p dot
                // softmax over j (no max-subtract; |lg| is small): butterfly
                float e = __expf(lg);
                float se = e;
                #pragma unroll
                for (int mk = 2; mk <= 32; mk <<= 1)
                    se += __shfl_xor(se, mk, 64);
                float c = e * __builtin_amdgcn_rcpf(se);
                #pragma unroll
                for (int pp = 0; pp < 8; ++pp)
                    Sa[bb][pp] = fmaf(c, uh[bb][pp], Sa[bb][pp]);
            }
        }

        if (nn + 1 < BN) {
            store_slice((nn + 1) & 1);
            __syncthreads();
        }
    }

    // ---- flush block-partial S ----
    #pragma unroll
    for (int bb = 0; bb < BT; ++bb) {
        const size_t off = ((size_t)(b0 + wave * BT + bb) * Jj + j) * Pp + hp * 8;
        if (ATOMIC) {
            float* sp = S + off;
            #pragma unroll
            for (int pp = 0; pp < 8; ++pp) atomicAdd(sp + pp, Sa[bb][pp]);
        } else {
            float4* dst = reinterpret_cast<float4*>(S + (size_t)nc * SZ + off);
            dst[0] = make_float4(Sa[bb][0], Sa[bb][1], Sa[bb][2], Sa[bb][3]);
            dst[1] = make_float4(Sa[bb][4], Sa[bb][5], Sa[bb][6], Sa[bb][7]);
        }
    }
}

// Reduce nparts partial S slices, then squash.
// mode 0: OS = v; 1: OS += v; 2: out = v.  One thread per float4 (16384).
__global__ void reduce_squash_k(const float* __restrict__ Sp, int nparts,
                                float scale, float* __restrict__ OS,
                                float* __restrict__ out, int mode)
{
    const int t = blockIdx.x * 256 + threadIdx.x;   // 0..16383
    const float4* sp = reinterpret_cast<const float4*>(Sp);
    float4 a = make_float4(0.f, 0.f, 0.f, 0.f);
    #pragma unroll 4
    for (int s = 0; s < nparts; ++s) {
        float4 v = sp[(size_t)s * (SZ / 4) + t];
        a.x += v.x; a.y += v.y; a.z += v.z; a.w += v.w;
    }
    a.x *= scale; a.y *= scale; a.z *= scale; a.w *= scale;
    float s2 = a.x * a.x + a.y * a.y + a.z * a.z + a.w * a.w;
    s2 += __shfl_xor(s2, 1, 64);   // 16 p = 4 consecutive threads
    s2 += __shfl_xor(s2, 2, 64);
    const float g = s2 / ((1.f + s2) * sqrtf(s2 + 1e-7f));
    float4 v = make_float4(g * a.x, g * a.y, g * a.z, g * a.w);
    if (mode == 0) {
        reinterpret_cast<float4*>(OS)[t] = v;
    } else if (mode == 1) {
        float4 o = reinterpret_cast<float4*>(OS)[t];
        o.x += v.x; o.y += v.y; o.z += v.z; o.w += v.w;
        reinterpret_cast<float4*>(OS)[t] = o;
    } else {
        reinterpret_cast<float4*>(out)[t] = v;
    }
}

extern "C" void kernel_launch(void* const* d_in, const int* in_sizes, int n_in,
                              void* d_out, int out_size, void* d_ws, size_t ws_size,
                              hipStream_t stream)
{
    const float* x = (const float*)d_in[0];   // [128, 2048, 8]
    const float* W = (const float*)d_in[1];   // [32, 2048, 16, 8]
    float* out = (float*)d_out;               // [128, 32, 16]

    const bool part = ws_size >= (size_t)(NNC + 1) * SZ * sizeof(float); // 16.9 MB
    dim3 rg(GRID), rb(512);
    dim3 sg(SZ / 4 / 256), sb(256);           // 64 blocks x 256

    if (part) {
        float* Sp = (float*)d_ws;                 // [64][65536] partials
        float* OS = Sp + (size_t)NNC * SZ;

        route_k<0, 0><<<rg, rb, 0, stream>>>(x, W, nullptr, Sp);
        reduce_squash_k<<<sg, sb, 0, stream>>>(Sp, NNC, 1.f / Jj, OS, out, 0);

        route_k<1, 0><<<rg, rb, 0, stream>>>(x, W, OS, Sp);
        reduce_squash_k<<<sg, sb, 0, stream>>>(Sp, NNC, 1.f, OS, out, 1);

        route_k<1, 0><<<rg, rb, 0, stream>>>(x, W, OS, Sp);
        reduce_squash_k<<<sg, sb, 0, stream>>>(Sp, NNC, 1.f, OS, out, 2);
    } else {
        float* S  = (float*)d_ws;
        float* OS = S + SZ;
        const size_t Sbytes = (size_t)SZ * sizeof(float);

        hipMemsetAsync(S, 0, Sbytes, stream);
        route_k<0, 1><<<rg, rb, 0, stream>>>(x, W, nullptr, S);
        reduce_squash_k<<<sg, sb, 0, stream>>>(S, 1, 1.f / Jj, OS, out, 0);

        hipMemsetAsync(S, 0, Sbytes, stream);
        route_k<1, 1><<<rg, rb, 0, stream>>>(x, W, OS, S);
        reduce_squash_k<<<sg, sb, 0, stream>>>(S, 1, 1.f, OS, out, 1);

        hipMemsetAsync(S, 0, Sbytes, stream);
        route_k<1, 1><<<rg, rb, 0, stream>>>(x, W, OS, S);
        reduce_squash_k<<<sg, sb, 0, stream>>>(S, 1, 1.f, OS, out, 2);
    }
}